// Round 4
// baseline (172.789 us; speedup 1.0000x reference)
//
#include <hip/hip_runtime.h>
#include <math.h>

#define BATCH 8
#define DIMD  512
#define NTOK  1024
#define NH    8
#define CQKV  640
#define DOUT  512

typedef __attribute__((ext_vector_type(8))) short short8;
typedef __attribute__((ext_vector_type(4))) short short4v;
typedef __attribute__((ext_vector_type(4))) float f32x4;

__device__ __forceinline__ short bf16rn(float x) {
    unsigned u = __float_as_uint(x);
    u += 0x7FFF + ((u >> 16) & 1);
    return (short)(u >> 16);
}
__device__ __forceinline__ float bf16tof(short s) {
    return __uint_as_float(((unsigned)(unsigned short)s) << 16);
}
struct HL { short h, l; };
__device__ __forceinline__ HL bf16split(float x) {
    HL r;
    r.h = bf16rn(x);
    r.l = bf16rn(x - bf16tof(r.h));
    return r;
}
__device__ __forceinline__ void dma16(const short* g, short* l) {
    __builtin_amdgcn_global_load_lds(
        (const __attribute__((address_space(1))) unsigned int*)g,
        (__attribute__((address_space(3))) unsigned int*)l, 16, 0, 0);
}
// max over the 16-lane r-group: ds_swizzle xor 1,2,4,8
__device__ __forceinline__ float swzmax16(float v) {
    v = fmaxf(v, __int_as_float(__builtin_amdgcn_ds_swizzle(__float_as_int(v), 0x041F)));
    v = fmaxf(v, __int_as_float(__builtin_amdgcn_ds_swizzle(__float_as_int(v), 0x081F)));
    v = fmaxf(v, __int_as_float(__builtin_amdgcn_ds_swizzle(__float_as_int(v), 0x101F)));
    v = fmaxf(v, __int_as_float(__builtin_amdgcn_ds_swizzle(__float_as_int(v), 0x201F)));
    return v;
}
// pack (truncate) two f32 -> two bf16 in one dword
__device__ __forceinline__ unsigned packbf2(float f0, float f1) {
    return __builtin_amdgcn_perm(__float_as_uint(f1), __float_as_uint(f0), 0x07060302);
}

// Fragment-order conventions (verified end-to-end R2/R4-R13):
//  A-frag: lane=(q,r), element A[m=r][k=q*8+j] per 32-k chunk
//  B-frag: element B[ncol=r][k=q*8+j]
//  C/D   : D[m=q*4+reg][ncol=r]
// K/V frag buffers: [b][t16][ic8][lane64][j8]; Q: [b][h][nt64][kc2][lane64][j8]
// O frag buffer:    [b][nt64][ct16][lane64][j8]

// ---------------------------------------------------------------------------
// prepack_all: fused prepack_x (blocks 0-1023) + prepack_w (1024-1183) +
// prepack_wout (1184-1311).  (unchanged from R13)
// ---------------------------------------------------------------------------
__global__ __launch_bounds__(256) void prepack_all(const float* __restrict__ x,
                                                   const float* __restrict__ qp,
                                                   const float* __restrict__ kp,
                                                   const float* __restrict__ vp,
                                                   const float* __restrict__ wout,
                                                   short* __restrict__ whi,
                                                   short* __restrict__ wlo,
                                                   short* __restrict__ xhi,
                                                   short* __restrict__ xlo,
                                                   short* __restrict__ wof) {
    __shared__ float Cs[64][65];
    const int blk = blockIdx.x;
    const int t = threadIdx.x;
    if (blk < 1024) {
        const int nt = blk & 15, dt = (blk >> 4) & 7, b = blk >> 7;
        #pragma unroll
        for (int i = 0; i < 4; ++i) {
            int row = (t >> 4) + i * 16;
            float4 v = *(const float4*)(x + ((size_t)(b * DIMD + dt * 64 + row)) * NTOK
                                          + nt * 64 + (t & 15) * 4);
            Cs[row][(t & 15) * 4 + 0] = v.x;
            Cs[row][(t & 15) * 4 + 1] = v.y;
            Cs[row][(t & 15) * 4 + 2] = v.z;
            Cs[row][(t & 15) * 4 + 3] = v.w;
        }
        __syncthreads();
        for (int u = t; u < 512; u += 256) {
            int lane2 = u & 63, cidx = u >> 6;
            int q2 = lane2 >> 4, r2 = lane2 & 15;
            int kt_loc = cidx & 1, mt_loc = cidx >> 1;
            short8 h8, l8;
            #pragma unroll
            for (int j = 0; j < 8; ++j) {
                HL s = bf16split(Cs[kt_loc * 32 + q2 * 8 + j][mt_loc * 16 + r2]);
                h8[j] = s.h; l8[j] = s.l;
            }
            size_t off = (((size_t)(b * 64 + nt * 4 + mt_loc)) * 16 + dt * 2 + kt_loc) * 512
                         + lane2 * 8;
            *(short8*)&xhi[off] = h8;
            *(short8*)&xlo[off] = l8;
        }
    } else if (blk < 1184) {
        int tid = (blk - 1024) * 256 + t;
        int lane = tid & 63, kt = (tid >> 6) & 15, ct = tid >> 10;
        int q = lane >> 4, r = lane & 15;
        int c = ct * 16 + r;
        short8 h, l;
        #pragma unroll
        for (int j = 0; j < 8; ++j) {
            int d = kt * 32 + q * 8 + j;
            float v;
            if (c < 64)       v = kp[d * 64 + c];
            else if (c < 128) v = vp[d * 64 + (c - 64)];
            else              v = qp[(size_t)(c - 128) * DIMD + d];
            HL s = bf16split(v);
            h[j] = s.h; l[j] = s.l;
        }
        *(short8*)&whi[(size_t)tid * 8] = h;
        *(short8*)&wlo[(size_t)tid * 8] = l;
    } else {
        int tid = (blk - 1184) * 256 + t;
        int lane = tid & 63, kt = (tid >> 6) & 15, mt = tid >> 10;
        int q = lane >> 4, r = lane & 15;
        const float* src = wout + (size_t)(mt * 16 + r) * DOUT + kt * 32 + q * 8;
        short8 h;
        #pragma unroll
        for (int j = 0; j < 8; ++j) h[j] = bf16rn(src[j]);
        *(short8*)&wof[(size_t)tid * 8] = h;
    }
}

// ---------------------------------------------------------------------------
// qkv_gemm: split-bf16 MFMA + fused frag emission.  BM=128(n) BN=64(c):
// each wave owns 2 row-tiles so every B ds_read_b128 feeds 6 MFMAs.
// Grid 640, XCD swizzle.  LDS: 48 KB staging / Cs[128][65] epilogue alias.
// (unchanged this round)
// ---------------------------------------------------------------------------
__global__ __launch_bounds__(256) void qkv_gemm(const short* __restrict__ xhi,
                                                const short* __restrict__ xlo,
                                                const short* __restrict__ whi,
                                                const short* __restrict__ wlo,
                                                short* __restrict__ khi,
                                                short* __restrict__ klo,
                                                short* __restrict__ vf,
                                                short* __restrict__ qhi,
                                                short* __restrict__ qlo) {
    __shared__ __align__(16) char pool[49152];
    short* Ah = (short*)pool;            // 8192 shorts (16 KB)
    short* Al = Ah + 8192;               // 16 KB
    short* Bh = Al + 8192;               // 4096 shorts (8 KB)
    short* Bl = Bh + 4096;               // 8 KB
    float (*Cs)[65] = (float(*)[65])pool;   // 128*65*4 = 33280 B (alias)

    // XCD swizzle: idx = (g&7) + 8*((g>>3)*10 + cb), g = M-tile id [0,64)
    const int idx = blockIdx.x;
    const int low = idx & 7, rest = idx >> 3;
    const int cb = rest % 10, gh = rest / 10;
    const int g = gh * 8 + low;
    const int b = g >> 3, bml = g & 7;      // rows n0 = bml*128

    const int tid = threadIdx.x, w = tid >> 6, lane = tid & 63;
    const int q = lane >> 4, r = lane & 15;
    f32x4 acc[2][4];
    #pragma unroll
    for (int i = 0; i < 2; ++i)
        #pragma unroll
        for (int j = 0; j < 4; ++j) acc[i][j] = (f32x4){0.f, 0.f, 0.f, 0.f};

    for (int it = 0; it < 8; ++it) {
        __syncthreads();
        for (int u = w; u < 16; u += 4) {
            size_t ga = ((size_t)((b * 64 + bml * 8 + (u >> 1)) * 16 + it * 2 + (u & 1))) * 512 + lane * 8;
            dma16(xhi + ga, &Ah[u * 512]);
            dma16(xlo + ga, &Al[u * 512]);
            if (u < 8) {
                size_t gb = ((size_t)((cb * 4 + (u >> 1)) * 16 + it * 2 + (u & 1))) * 512 + lane * 8;
                dma16(whi + gb, &Bh[u * 512]);
                dma16(wlo + gb, &Bl[u * 512]);
            }
        }
        __syncthreads();
        #pragma unroll
        for (int kc = 0; kc < 2; ++kc) {
            short8 ah[2], al[2];
            #pragma unroll
            for (int rt = 0; rt < 2; ++rt) {
                ah[rt] = *(short8*)&Ah[((w * 2 + rt) * 2 + kc) * 512 + lane * 8];
                al[rt] = *(short8*)&Al[((w * 2 + rt) * 2 + kc) * 512 + lane * 8];
            }
            #pragma unroll
            for (int tt = 0; tt < 4; ++tt) {
                short8 bh = *(short8*)&Bh[(tt * 2 + kc) * 512 + lane * 8];
                short8 bl = *(short8*)&Bl[(tt * 2 + kc) * 512 + lane * 8];
                #pragma unroll
                for (int rt = 0; rt < 2; ++rt) {
                    acc[rt][tt] = __builtin_amdgcn_mfma_f32_16x16x32_bf16(ah[rt], bh, acc[rt][tt], 0, 0, 0);
                    acc[rt][tt] = __builtin_amdgcn_mfma_f32_16x16x32_bf16(ah[rt], bl, acc[rt][tt], 0, 0, 0);
                    acc[rt][tt] = __builtin_amdgcn_mfma_f32_16x16x32_bf16(al[rt], bh, acc[rt][tt], 0, 0, 0);
                }
            }
        }
    }

    // ---- fused epilogue: C tile (128x64) -> LDS -> frag-order bf16 global ----
    __syncthreads();
    #pragma unroll
    for (int rt = 0; rt < 2; ++rt)
        #pragma unroll
        for (int reg = 0; reg < 4; ++reg)
            #pragma unroll
            for (int tt = 0; tt < 4; ++tt)
                Cs[w * 32 + rt * 16 + q * 4 + reg][tt * 16 + r] = acc[rt][tt][reg];
    __syncthreads();

    if (cb == 0) {
        // K: 2 t-tiles; elem K[m=t*64+i*16+r2][kd=cc*32+q2*8+j], ic=i*2+cc
        for (int u = tid; u < 1024; u += 256) {
            int lane2 = u & 63, ic = (u >> 6) & 7, tl = u >> 9;
            int q2 = lane2 >> 4, r2 = lane2 & 15;
            int i = ic >> 1, cc = ic & 1;
            short8 h8, l8;
            #pragma unroll
            for (int j = 0; j < 8; ++j) {
                HL s = bf16split(Cs[tl * 64 + i * 16 + r2][cc * 32 + q2 * 8 + j]);
                h8[j] = s.h; l8[j] = s.l;
            }
            size_t off = ((size_t)(b * 16 + bml * 2 + tl) * 8 + ic) * 512 + lane2 * 8;
            *(short8*)&khi[off] = h8;
            *(short8*)&klo[off] = l8;
        }
    } else if (cb == 1) {
        // V: 2 t-tiles; elem V[m=cc*32+q2*8+j][v=tv*16+r2], ic=tv*2+cc
        for (int u = tid; u < 1024; u += 256) {
            int lane2 = u & 63, ic = (u >> 6) & 7, tl = u >> 9;
            int q2 = lane2 >> 4, r2 = lane2 & 15;
            int tv = ic >> 1, cc = ic & 1;
            short8 v8;
            #pragma unroll
            for (int j = 0; j < 8; ++j)
                v8[j] = bf16rn(Cs[tl * 64 + cc * 32 + q2 * 8 + j][tv * 16 + r2]);
            size_t off = ((size_t)(b * 16 + bml * 2 + tl) * 8 + ic) * 512 + lane2 * 8;
            *(short8*)&vf[off] = v8;
        }
    } else {
        // Q head hd: 8 nt-tiles x 2 kc = 16 chunks -> u < 1024 (R14 bug: was 2048)
        const int hd = cb - 2;
        const float qscale = 0.125f * 1.44269504f;
        for (int u = tid; u < 1024; u += 256) {
            int lane2 = u & 63, ch = u >> 6;        // ch in [0,16)
            int q2 = lane2 >> 4, r2 = lane2 & 15;
            int kc = ch & 1, ntl = ch >> 1;         // ntl in [0,8)
            short8 h8, l8;
            #pragma unroll
            for (int j = 0; j < 8; ++j) {
                HL s = bf16split(Cs[ntl * 16 + r2][kc * 32 + q2 * 8 + j] * qscale);
                h8[j] = s.h; l8[j] = s.l;
            }
            size_t off = ((((size_t)(b * 8 + hd) * 64 + bml * 8 + ntl) * 2 + kc) * 64 + lane2) * 8;
            *(short8*)&qhi[off] = h8;
            *(short8*)&qlo[off] = l8;
        }
    }
}

// ---------------------------------------------------------------------------
// attn: R18.  R16 post-mortem: LDS-pipe-bound (~43 µs of 60.6 µs was
// ds_read_b128 K/V frag traffic: 24 b128/tile/wave x 4096 waves x 16 tiles).
// K/V frag arrays are ALREADY in exact MFMA fragment order in global memory,
// and per-b K/V (1.5 MB) fits the per-XCD L2 (blocks XCD-swizzled by b).
// So: read K/V fragments DIRECTLY global->VGPR (coalesced dwordx4, L1/L2
// hits); delete the entire LDS staging path, the double buffer, and ALL
// main-loop barriers (Pbuf is per-wave; waves run free).  LDS = 20 KB Pbuf
// only.  __launch_bounds__(512,4) caps VGPR at 128 -> 2 blocks/CU =
// 16 waves/CU.  L2 latency (~200cy) hides under 4 waves/SIMD + batched
// independent loads.
// ---------------------------------------------------------------------------
__global__ __launch_bounds__(512, 4) void attn_mfma(const short* __restrict__ qhi_g,
                                                    const short* __restrict__ qlo_g,
                                                    const short* __restrict__ khi_g,
                                                    const short* __restrict__ klo_g,
                                                    const short* __restrict__ vf_g,
                                                    short* __restrict__ ob) {
    __shared__ short Pbuf[8 * 64 * 20];                          // 20 KB
    const int blk = blockIdx.x;
    const int b   = blk & 7;        // XCD = blk%8 = b -> per-XCD K/V L2 locality
    const int h   = (blk >> 3) & 7;
    const int qt  = blk >> 6;
    const int tid = threadIdx.x;
    const int w    = tid >> 6;      // 8 waves
    const int lane = tid & 63;
    const int q    = lane >> 4;
    const int r    = lane & 15;
    short* Pw = Pbuf + w * (64 * 20);
    const int nt = qt * 8 + w;      // this wave's 16-row q-tile

    short8 qhi[2], qlo[2];
    #pragma unroll
    for (int c = 0; c < 2; ++c) {
        size_t off = ((((size_t)(b * 8 + h) * 64 + nt) * 2 + c) * 64 + lane) * 8;
        qhi[c] = *(const short8*)&qhi_g[off];
        qlo[c] = *(const short8*)&qlo_g[off];
    }

    short8 bones;
    #pragma unroll
    for (int j = 0; j < 8; ++j) bones[j] = (short)0x3F80;

    f32x4 oacc[4], lacc;
    float m_[4];
    #pragma unroll
    for (int tt = 0; tt < 4; ++tt) oacc[tt] = (f32x4){0.f, 0.f, 0.f, 0.f};
    lacc = (f32x4){0.f, 0.f, 0.f, 0.f};
    #pragma unroll
    for (int i = 0; i < 4; ++i) m_[i] = -1e30f;

    for (int t = 0; t < 16; ++t) {
        // base of this KV tile's frag block: [b][t][ic8][lane64][j8]
        const size_t kb = ((size_t)(b * 16 + t) * 8) * 512 + (size_t)lane * 8;

        // ---- QK^T: S[m=16 rows][64 keys], split-bf16 3-term ----
        // K frags straight from global (frag-order; L1/L2-hit)
        f32x4 s[4];
        #pragma unroll
        for (int tt = 0; tt < 4; ++tt) s[tt] = (f32x4){0.f, 0.f, 0.f, 0.f};
        #pragma unroll
        for (int c = 0; c < 2; ++c) {
            #pragma unroll
            for (int tt = 0; tt < 4; ++tt) {
                short8 kh = *(const short8*)&khi_g[kb + (tt * 2 + c) * 512];
                short8 kl = *(const short8*)&klo_g[kb + (tt * 2 + c) * 512];
                s[tt] = __builtin_amdgcn_mfma_f32_16x16x32_bf16(qhi[c], kh, s[tt], 0, 0, 0);
                s[tt] = __builtin_amdgcn_mfma_f32_16x16x32_bf16(qhi[c], kl, s[tt], 0, 0, 0);
                s[tt] = __builtin_amdgcn_mfma_f32_16x16x32_bf16(qlo[c], kh, s[tt], 0, 0, 0);
            }
        }

        // ---- lazy online softmax (log2 space) ----
        float pmax[4];
        bool need = false;
        #pragma unroll
        for (int reg = 0; reg < 4; ++reg) {
            float pm = fmaxf(fmaxf(s[0][reg], s[1][reg]), fmaxf(s[2][reg], s[3][reg]));
            pmax[reg] = pm;
            need = need || (pm > m_[reg] + 30.f);
        }
        if (__any((int)need)) {
            #pragma unroll
            for (int reg = 0; reg < 4; ++reg) {
                float smax = swzmax16(pmax[reg]);
                float nm    = fmaxf(m_[reg], smax);
                float alpha = exp2f(m_[reg] - nm);
                m_[reg] = nm;
                lacc[reg] *= alpha;
                #pragma unroll
                for (int tt = 0; tt < 4; ++tt) oacc[tt][reg] *= alpha;
            }
        }
        #pragma unroll
        for (int reg = 0; reg < 4; ++reg)
            #pragma unroll
            for (int tt = 0; tt < 4; ++tt)
                s[tt][reg] = exp2f(s[tt][reg] - m_[reg]);

        // ---- P -> LDS (P^T layout [key][m], stride 20 shorts, 8B-aligned) ----
        #pragma unroll
        for (int tt = 0; tt < 4; ++tt) {
            uint2 pk;
            pk.x = packbf2(s[tt][0], s[tt][1]);
            pk.y = packbf2(s[tt][2], s[tt][3]);
            *(uint2*)&Pw[(r + 16 * tt) * 20 + q * 4] = pk;
        }

        // ---- PV + row-sum via MFMA (V frags straight from global) ----
        #pragma unroll
        for (int c = 0; c < 2; ++c) {
            short8 pf;
            #pragma unroll
            for (int j = 0; j < 8; ++j)
                pf[j] = Pw[(c * 32 + q * 8 + j) * 20 + r];
            lacc = __builtin_amdgcn_mfma_f32_16x16x32_bf16(pf, bones, lacc, 0, 0, 0);
            #pragma unroll
            for (int tt = 0; tt < 4; ++tt) {
                short8 vfr = *(const short8*)&vf_g[kb + (tt * 2 + c) * 512];
                oacc[tt] = __builtin_amdgcn_mfma_f32_16x16x32_bf16(pf, vfr, oacc[tt], 0, 0, 0);
            }
        }
    }

    // ---- epilogue: O frag-order bf16 store ----
    #pragma unroll
    for (int reg = 0; reg < 4; ++reg) {
        float inv = 1.f / lacc[reg];
        #pragma unroll
        for (int tt = 0; tt < 4; ++tt) {
            int ct = h * 2 + (tt >> 1);
            int lanep = ((tt & 1) * 2 + (r >> 3)) * 16 + q * 4 + reg;
            ob[((((size_t)b * 64 + nt) * 16 + ct) * 64 + lanep) * 8 + (r & 7)] =
                bf16rn(oacc[tt][reg] * inv);
        }
    }
}

// ---------------------------------------------------------------------------
// out_gemm: plain bf16 MFMA, double-buffered staging (unchanged).
// ---------------------------------------------------------------------------
__global__ __launch_bounds__(256) void out_gemm(const short* __restrict__ wof,
                                                const short* __restrict__ obf,
                                                float* __restrict__ out) {
    __shared__ short Ah[2][4096];
    __shared__ short Bh[2][4096];
    const int b = blockIdx.z, bd = blockIdx.y, bn = blockIdx.x;
    const int tid = threadIdx.x, w = tid >> 6, lane = tid & 63;
    const int q = lane >> 4, r = lane & 15;
    f32x4 acc[4];
    #pragma unroll
    for (int j = 0; j < 4; ++j) acc[j] = (f32x4){0.f, 0.f, 0.f, 0.f};

    for (int u = w; u < 8; u += 4) {
        size_t ga = ((size_t)((bd * 4 + (u >> 1)) * 16 + (u & 1))) * 512 + lane * 8;
        dma16(wof + ga, &Ah[0][u * 512]);
        size_t gb = ((size_t)((b * 64 + bn * 4 + (u >> 1)) * 16 + (u & 1))) * 512 + lane * 8;
        dma16(obf + gb, &Bh[0][u * 512]);
    }

    for (int it = 0; it < 8; ++it) {
        const int cur = it & 1;
        __syncthreads();
        if (it < 7) {
            for (int u = w; u < 8; u += 4) {
                size_t ga = ((size_t)((bd * 4 + (u >> 1)) * 16 + (it + 1) * 2 + (u & 1))) * 512 + lane * 8;
                dma16(wof + ga, &Ah[cur ^ 1][u * 512]);
                size_t gb = ((size_t)((b * 64 + bn * 4 + (u >> 1)) * 16 + (it + 1) * 2 + (u & 1))) * 512 + lane * 8;
                dma16(obf + gb, &Bh[cur ^ 1][u * 512]);
            }
        }
        #pragma unroll
        for (int kc = 0; kc < 2; ++kc) {
            short8 a = *(short8*)&Ah[cur][(w * 2 + kc) * 512 + lane * 8];
            #pragma unroll
            for (int tt = 0; tt < 4; ++tt) {
                short8 bb = *(short8*)&Bh[cur][(tt * 2 + kc) * 512 + lane * 8];
                acc[tt] = __builtin_amdgcn_mfma_f32_16x16x32_bf16(a, bb, acc[tt], 0, 0, 0);
            }
        }
    }
    const int d_base = bd * 64 + w * 16;
    #pragma unroll
    for (int reg = 0; reg < 4; ++reg)
        #pragma unroll
        for (int tt = 0; tt < 4; ++tt)
            out[((size_t)b * DOUT + d_base + q * 4 + reg) * NTOK
                + bn * 64 + tt * 16 + r] = acc[tt][reg];
}

// ---------------------------------------------------------------------------
extern "C" void kernel_launch(void* const* d_in, const int* in_sizes, int n_in,
                              void* d_out, int out_size, void* d_ws, size_t ws_size,
                              hipStream_t stream) {
    const float* x  = (const float*)d_in[0];
    const float* qp = (const float*)d_in[1];
    const float* kp = (const float*)d_in[2];
    const float* vp = (const float*)d_in[3];
    const float* op = (const float*)d_in[4];
    float* out = (float*)d_out;

    // workspace: 38.5 MB (proven R12/R13)
    short* Whi = (short*)d_ws;                 // 327,680
    short* Wlo = Whi + 327680;                 // 327,680
    short* Xhi = Wlo + 327680;                 // 4,194,304
    short* Xlo = Xhi + 4194304;                // 4,194,304
    short* Qhi = Xlo + 4194304;                // 4,194,304
    short* Qlo = Qhi + 4194304;                // 4,194,304
    short* Khi = Qlo + 4194304;                // 524,288
    short* Klo = Khi + 524288;                 // 524,288
    short* Vf  = Klo + 524288;                 // 524,288
    short* Wof = Vf  + 524288;                 // 262,144
    short* Ob  = Xhi;                          // alias: X dead after qkv_gemm

    prepack_all <<<1312, 256, 0, stream>>>(x, qp, kp, vp, op,
                                           Whi, Wlo, Xhi, Xlo, Wof);
    qkv_gemm    <<<640, 256, 0, stream>>>(Xhi, Xlo, Whi, Wlo,
                                          Khi, Klo, Vf, Qhi, Qlo);
    attn_mfma   <<<512, 512, 0, stream>>>(Qhi, Qlo, Khi, Klo, Vf, Ob);
    out_gemm    <<<dim3(16, 8, BATCH), 256, 0, stream>>>(Wof, Ob, out);
}

// Round 5
// 155.413 us; speedup vs baseline: 1.1118x; 1.1118x over previous
//
#include <hip/hip_runtime.h>
#include <math.h>

#define BATCH 8
#define DIMD  512
#define NTOK  1024
#define NH    8
#define CQKV  640
#define DOUT  512

typedef __attribute__((ext_vector_type(8))) short short8;
typedef __attribute__((ext_vector_type(4))) short short4v;
typedef __attribute__((ext_vector_type(4))) float f32x4;

__device__ __forceinline__ short bf16rn(float x) {
    unsigned u = __float_as_uint(x);
    u += 0x7FFF + ((u >> 16) & 1);
    return (short)(u >> 16);
}
__device__ __forceinline__ float bf16tof(short s) {
    return __uint_as_float(((unsigned)(unsigned short)s) << 16);
}
struct HL { short h, l; };
__device__ __forceinline__ HL bf16split(float x) {
    HL r;
    r.h = bf16rn(x);
    r.l = bf16rn(x - bf16tof(r.h));
    return r;
}
__device__ __forceinline__ void dma16(const short* g, short* l) {
    __builtin_amdgcn_global_load_lds(
        (const __attribute__((address_space(1))) unsigned int*)g,
        (__attribute__((address_space(3))) unsigned int*)l, 16, 0, 0);
}
// pack (truncate) two f32 -> two bf16 in one dword (lo = f0, hi = f1)
__device__ __forceinline__ unsigned packbf2(float f0, float f1) {
    return __builtin_amdgcn_perm(__float_as_uint(f1), __float_as_uint(f0), 0x07060302);
}

// 16x16x16 bf16 MFMA (A,B: 4 bf16 = 2 VGPR).  Builtin name varies across
// ROCm versions; fall back to inline asm with an s_nop hazard guard (the
// compiler's hazard recognizer cannot see into asm, so we pad VALU->MFMA).
#if defined(__has_builtin)
#if __has_builtin(__builtin_amdgcn_mfma_f32_16x16x16bf16_1k)
#define HAVE_MFMA16_BUILTIN 1
__device__ __forceinline__ f32x4 mfma16(short4v a, short4v b, f32x4 c) {
    return __builtin_amdgcn_mfma_f32_16x16x16bf16_1k(a, b, c, 0, 0, 0);
}
#elif __has_builtin(__builtin_amdgcn_mfma_f32_16x16x16_bf16)
#define HAVE_MFMA16_BUILTIN 1
__device__ __forceinline__ f32x4 mfma16(short4v a, short4v b, f32x4 c) {
    return __builtin_amdgcn_mfma_f32_16x16x16_bf16(a, b, c, 0, 0, 0);
}
#endif
#endif
#ifndef HAVE_MFMA16_BUILTIN
__device__ __forceinline__ f32x4 mfma16(short4v a, short4v b, f32x4 c) {
    asm("s_nop 1\n\tv_mfma_f32_16x16x16_bf16 %0, %1, %2, %0"
        : "+v"(c) : "v"(a), "v"(b));
    return c;
}
#endif

// Fragment-order conventions (verified end-to-end R2/R4-R13):
//  A-frag (16x16x32): lane=(q,r), element A[m=r][k=q*8+j]; B-frag identical.
//  A/B-frag (16x16x16): lane=(q,r), element [r][k=q*4+j], j=0..3.
//  C/D   : D[m=q*4+reg][ncol=r]
// K/V frag buffers: [b][t16][ic8][lane64][j8]; Q: [b][h][nt64][kc2][lane64][j8]
// O frag buffer:    [b][nt64][ct16][lane64][j8]

// ---------------------------------------------------------------------------
// prepack_all: fused prepack_x (blocks 0-1023) + prepack_w (1024-1183) +
// prepack_wout (1184-1311).  (unchanged from R13)
// ---------------------------------------------------------------------------
__global__ __launch_bounds__(256) void prepack_all(const float* __restrict__ x,
                                                   const float* __restrict__ qp,
                                                   const float* __restrict__ kp,
                                                   const float* __restrict__ vp,
                                                   const float* __restrict__ wout,
                                                   short* __restrict__ whi,
                                                   short* __restrict__ wlo,
                                                   short* __restrict__ xhi,
                                                   short* __restrict__ xlo,
                                                   short* __restrict__ wof) {
    __shared__ float Cs[64][65];
    const int blk = blockIdx.x;
    const int t = threadIdx.x;
    if (blk < 1024) {
        const int nt = blk & 15, dt = (blk >> 4) & 7, b = blk >> 7;
        #pragma unroll
        for (int i = 0; i < 4; ++i) {
            int row = (t >> 4) + i * 16;
            float4 v = *(const float4*)(x + ((size_t)(b * DIMD + dt * 64 + row)) * NTOK
                                          + nt * 64 + (t & 15) * 4);
            Cs[row][(t & 15) * 4 + 0] = v.x;
            Cs[row][(t & 15) * 4 + 1] = v.y;
            Cs[row][(t & 15) * 4 + 2] = v.z;
            Cs[row][(t & 15) * 4 + 3] = v.w;
        }
        __syncthreads();
        for (int u = t; u < 512; u += 256) {
            int lane2 = u & 63, cidx = u >> 6;
            int q2 = lane2 >> 4, r2 = lane2 & 15;
            int kt_loc = cidx & 1, mt_loc = cidx >> 1;
            short8 h8, l8;
            #pragma unroll
            for (int j = 0; j < 8; ++j) {
                HL s = bf16split(Cs[kt_loc * 32 + q2 * 8 + j][mt_loc * 16 + r2]);
                h8[j] = s.h; l8[j] = s.l;
            }
            size_t off = (((size_t)(b * 64 + nt * 4 + mt_loc)) * 16 + dt * 2 + kt_loc) * 512
                         + lane2 * 8;
            *(short8*)&xhi[off] = h8;
            *(short8*)&xlo[off] = l8;
        }
    } else if (blk < 1184) {
        int tid = (blk - 1024) * 256 + t;
        int lane = tid & 63, kt = (tid >> 6) & 15, ct = tid >> 10;
        int q = lane >> 4, r = lane & 15;
        int c = ct * 16 + r;
        short8 h, l;
        #pragma unroll
        for (int j = 0; j < 8; ++j) {
            int d = kt * 32 + q * 8 + j;
            float v;
            if (c < 64)       v = kp[d * 64 + c];
            else if (c < 128) v = vp[d * 64 + (c - 64)];
            else              v = qp[(size_t)(c - 128) * DIMD + d];
            HL s = bf16split(v);
            h[j] = s.h; l[j] = s.l;
        }
        *(short8*)&whi[(size_t)tid * 8] = h;
        *(short8*)&wlo[(size_t)tid * 8] = l;
    } else {
        int tid = (blk - 1184) * 256 + t;
        int lane = tid & 63, kt = (tid >> 6) & 15, mt = tid >> 10;
        int q = lane >> 4, r = lane & 15;
        const float* src = wout + (size_t)(mt * 16 + r) * DOUT + kt * 32 + q * 8;
        short8 h;
        #pragma unroll
        for (int j = 0; j < 8; ++j) h[j] = bf16rn(src[j]);
        *(short8*)&wof[(size_t)tid * 8] = h;
    }
}

// ---------------------------------------------------------------------------
// qkv_gemm: split-bf16 MFMA + fused frag emission.  (unchanged this round)
// ---------------------------------------------------------------------------
__global__ __launch_bounds__(256) void qkv_gemm(const short* __restrict__ xhi,
                                                const short* __restrict__ xlo,
                                                const short* __restrict__ whi,
                                                const short* __restrict__ wlo,
                                                short* __restrict__ khi,
                                                short* __restrict__ klo,
                                                short* __restrict__ vf,
                                                short* __restrict__ qhi,
                                                short* __restrict__ qlo) {
    __shared__ __align__(16) char pool[49152];
    short* Ah = (short*)pool;            // 8192 shorts (16 KB)
    short* Al = Ah + 8192;               // 16 KB
    short* Bh = Al + 8192;               // 4096 shorts (8 KB)
    short* Bl = Bh + 4096;               // 8 KB
    float (*Cs)[65] = (float(*)[65])pool;   // 128*65*4 = 33280 B (alias)

    // XCD swizzle: idx = (g&7) + 8*((g>>3)*10 + cb), g = M-tile id [0,64)
    const int idx = blockIdx.x;
    const int low = idx & 7, rest = idx >> 3;
    const int cb = rest % 10, gh = rest / 10;
    const int g = gh * 8 + low;
    const int b = g >> 3, bml = g & 7;      // rows n0 = bml*128

    const int tid = threadIdx.x, w = tid >> 6, lane = tid & 63;
    const int q = lane >> 4, r = lane & 15;
    f32x4 acc[2][4];
    #pragma unroll
    for (int i = 0; i < 2; ++i)
        #pragma unroll
        for (int j = 0; j < 4; ++j) acc[i][j] = (f32x4){0.f, 0.f, 0.f, 0.f};

    for (int it = 0; it < 8; ++it) {
        __syncthreads();
        for (int u = w; u < 16; u += 4) {
            size_t ga = ((size_t)((b * 64 + bml * 8 + (u >> 1)) * 16 + it * 2 + (u & 1))) * 512 + lane * 8;
            dma16(xhi + ga, &Ah[u * 512]);
            dma16(xlo + ga, &Al[u * 512]);
            if (u < 8) {
                size_t gb = ((size_t)((cb * 4 + (u >> 1)) * 16 + it * 2 + (u & 1))) * 512 + lane * 8;
                dma16(whi + gb, &Bh[u * 512]);
                dma16(wlo + gb, &Bl[u * 512]);
            }
        }
        __syncthreads();
        #pragma unroll
        for (int kc = 0; kc < 2; ++kc) {
            short8 ah[2], al[2];
            #pragma unroll
            for (int rt = 0; rt < 2; ++rt) {
                ah[rt] = *(short8*)&Ah[((w * 2 + rt) * 2 + kc) * 512 + lane * 8];
                al[rt] = *(short8*)&Al[((w * 2 + rt) * 2 + kc) * 512 + lane * 8];
            }
            #pragma unroll
            for (int tt = 0; tt < 4; ++tt) {
                short8 bh = *(short8*)&Bh[(tt * 2 + kc) * 512 + lane * 8];
                short8 bl = *(short8*)&Bl[(tt * 2 + kc) * 512 + lane * 8];
                #pragma unroll
                for (int rt = 0; rt < 2; ++rt) {
                    acc[rt][tt] = __builtin_amdgcn_mfma_f32_16x16x32_bf16(ah[rt], bh, acc[rt][tt], 0, 0, 0);
                    acc[rt][tt] = __builtin_amdgcn_mfma_f32_16x16x32_bf16(ah[rt], bl, acc[rt][tt], 0, 0, 0);
                    acc[rt][tt] = __builtin_amdgcn_mfma_f32_16x16x32_bf16(al[rt], bh, acc[rt][tt], 0, 0, 0);
                }
            }
        }
    }

    // ---- fused epilogue: C tile (128x64) -> LDS -> frag-order bf16 global ----
    __syncthreads();
    #pragma unroll
    for (int rt = 0; rt < 2; ++rt)
        #pragma unroll
        for (int reg = 0; reg < 4; ++reg)
            #pragma unroll
            for (int tt = 0; tt < 4; ++tt)
                Cs[w * 32 + rt * 16 + q * 4 + reg][tt * 16 + r] = acc[rt][tt][reg];
    __syncthreads();

    if (cb == 0) {
        // K: 2 t-tiles; elem K[m=t*64+i*16+r2][kd=cc*32+q2*8+j], ic=i*2+cc
        for (int u = tid; u < 1024; u += 256) {
            int lane2 = u & 63, ic = (u >> 6) & 7, tl = u >> 9;
            int q2 = lane2 >> 4, r2 = lane2 & 15;
            int i = ic >> 1, cc = ic & 1;
            short8 h8, l8;
            #pragma unroll
            for (int j = 0; j < 8; ++j) {
                HL s = bf16split(Cs[tl * 64 + i * 16 + r2][cc * 32 + q2 * 8 + j]);
                h8[j] = s.h; l8[j] = s.l;
            }
            size_t off = ((size_t)(b * 16 + bml * 2 + tl) * 8 + ic) * 512 + lane2 * 8;
            *(short8*)&khi[off] = h8;
            *(short8*)&klo[off] = l8;
        }
    } else if (cb == 1) {
        // V: 2 t-tiles; elem V[m=cc*32+q2*8+j][v=tv*16+r2], ic=tv*2+cc
        for (int u = tid; u < 1024; u += 256) {
            int lane2 = u & 63, ic = (u >> 6) & 7, tl = u >> 9;
            int q2 = lane2 >> 4, r2 = lane2 & 15;
            int tv = ic >> 1, cc = ic & 1;
            short8 v8;
            #pragma unroll
            for (int j = 0; j < 8; ++j)
                v8[j] = bf16rn(Cs[tl * 64 + cc * 32 + q2 * 8 + j][tv * 16 + r2]);
            size_t off = ((size_t)(b * 16 + bml * 2 + tl) * 8 + ic) * 512 + lane2 * 8;
            *(short8*)&vf[off] = v8;
        }
    } else {
        // Q head hd: 8 nt-tiles x 2 kc = 16 chunks
        const int hd = cb - 2;
        const float qscale = 0.125f * 1.44269504f;
        for (int u = tid; u < 1024; u += 256) {
            int lane2 = u & 63, ch = u >> 6;        // ch in [0,16)
            int q2 = lane2 >> 4, r2 = lane2 & 15;
            int kc = ch & 1, ntl = ch >> 1;         // ntl in [0,8)
            short8 h8, l8;
            #pragma unroll
            for (int j = 0; j < 8; ++j) {
                HL s = bf16split(Cs[ntl * 16 + r2][kc * 32 + q2 * 8 + j] * qscale);
                h8[j] = s.h; l8[j] = s.l;
            }
            size_t off = ((((size_t)(b * 8 + hd) * 64 + bml * 8 + ntl) * 2 + kc) * 64 + lane2) * 8;
            *(short8*)&qhi[off] = h8;
            *(short8*)&qlo[off] = l8;
        }
    }
}

// ---------------------------------------------------------------------------
// attn: R19 — swapped QK^T (S^T = mfma(K,Q); A/B frag maps identical so no
// repack) makes each lane hold P[row=r][key=q*4+reg], which IS the 16x16x16
// PV A-fragment (k=q*4+j, j=reg).  P never leaves registers: Pbuf deleted
// (LDS 68->48 KB), 4 ds_write + 16 ds_read_u16 + addressing gone.  Softmax
// state m_ is scalar (row r); cross-lane shuffles only on lazy trigger, with
// 4 bpermutes redistributing alpha to oacc rows (q*4+reg).  V read from the
// SAME staged LDS layout as ds_read_b64 at immediate offsets (same bytes).
// K/V staging identical to R16 (dbuf + pinned vmcnt/lgkm drain; proven).
// R18 post-mortem: direct-global K/V regressed (L1 1KB/16cyc < LDS 1KB/8cyc)
// -> staging restored.
// ---------------------------------------------------------------------------
__global__ __launch_bounds__(512) void attn_mfma(const short* __restrict__ qhi_g,
                                                 const short* __restrict__ qlo_g,
                                                 const short* __restrict__ khi_g,
                                                 const short* __restrict__ klo_g,
                                                 const short* __restrict__ vf_g,
                                                 short* __restrict__ ob) {
    __shared__ short Khi[2][4096], Klo[2][4096], Vf[2][4096];   // 48 KB
    const int blk = blockIdx.x;
    const int b   = blk & 7;        // XCD = blk%8 = b -> per-XCD K/V L2 locality
    const int h   = (blk >> 3) & 7;
    const int qt  = blk >> 6;
    const int tid = threadIdx.x;
    const int w    = tid >> 6;      // 8 waves
    const int lane = tid & 63;
    const int q    = lane >> 4;
    const int r    = lane & 15;
    const int nt = qt * 8 + w;      // this wave's 16-row q-tile

    short8 qhi[2], qlo[2];
    #pragma unroll
    for (int c = 0; c < 2; ++c) {
        size_t off = ((((size_t)(b * 8 + h) * 64 + nt) * 2 + c) * 64 + lane) * 8;
        qhi[c] = *(const short8*)&qhi_g[off];
        qlo[c] = *(const short8*)&qlo_g[off];
    }

    short4v bones4;
    #pragma unroll
    for (int j = 0; j < 4; ++j) bones4[j] = (short)0x3F80;

    f32x4 oacc[4], lacc;
    #pragma unroll
    for (int tt = 0; tt < 4; ++tt) oacc[tt] = (f32x4){0.f, 0.f, 0.f, 0.f};
    lacc = (f32x4){0.f, 0.f, 0.f, 0.f};
    float m_ = -1e30f;              // running row-max (row = r), log2 space

    // per-lane LDS bases (in shorts)
    const int kbase = lane * 8;
    const int vbase = ((q >> 1) * 16 + r) * 8 + (q & 1) * 4;

    // prologue: DMA tile 0 into buffer 0 (each wave stages chunk ch = w)
    {
        const size_t kb = ((size_t)(b * 16 + 0) * 8) * 512;
        dma16(khi_g + kb + w * 512 + lane * 8, &Khi[0][w * 512]);
        dma16(klo_g + kb + w * 512 + lane * 8, &Klo[0][w * 512]);
        dma16(vf_g  + kb + w * 512 + lane * 8, &Vf [0][w * 512]);
    }

    for (int t = 0; t < 16; ++t) {
        const int cur = t & 1;
        // pinned drain: own DMA landed (vmcnt) AND own ds_reads retired (lgkm)
        // before the barrier; closes the trap-#18 race (proven R16/R17).
        __builtin_amdgcn_sched_barrier(0);
        asm volatile("s_waitcnt vmcnt(0) lgkmcnt(0)" ::: "memory");
        __builtin_amdgcn_sched_barrier(0);
        __syncthreads();
        if (t < 15) {               // issue next tile into buf[cur^1]
            const size_t kb = ((size_t)(b * 16 + t + 1) * 8) * 512;
            dma16(khi_g + kb + w * 512 + lane * 8, &Khi[cur ^ 1][w * 512]);
            dma16(klo_g + kb + w * 512 + lane * 8, &Klo[cur ^ 1][w * 512]);
            dma16(vf_g  + kb + w * 512 + lane * 8, &Vf [cur ^ 1][w * 512]);
        }

        // ---- swapped QK^T: sT[i] = S^T tile i, lane(q,r) reg:
        //      S[key=i*16+q*4+reg][row=r]  (split-bf16 3-term) ----
        f32x4 sT[4];
        #pragma unroll
        for (int i = 0; i < 4; ++i) sT[i] = (f32x4){0.f, 0.f, 0.f, 0.f};
        #pragma unroll
        for (int cc = 0; cc < 2; ++cc) {
            #pragma unroll
            for (int i = 0; i < 4; ++i) {
                short8 kh = *(short8*)&Khi[cur][(i * 2 + cc) * 512 + kbase];
                short8 kl = *(short8*)&Klo[cur][(i * 2 + cc) * 512 + kbase];
                sT[i] = __builtin_amdgcn_mfma_f32_16x16x32_bf16(kh, qhi[cc], sT[i], 0, 0, 0);
                sT[i] = __builtin_amdgcn_mfma_f32_16x16x32_bf16(kl, qhi[cc], sT[i], 0, 0, 0);
                sT[i] = __builtin_amdgcn_mfma_f32_16x16x32_bf16(kh, qlo[cc], sT[i], 0, 0, 0);
            }
        }

        // ---- lazy online softmax (log2 space; m_ scalar per lane = row r) ----
        float pm;
        {
            float a0 = fmaxf(fmaxf(sT[0][0], sT[0][1]), fmaxf(sT[0][2], sT[0][3]));
            float a1 = fmaxf(fmaxf(sT[1][0], sT[1][1]), fmaxf(sT[1][2], sT[1][3]));
            float a2 = fmaxf(fmaxf(sT[2][0], sT[2][1]), fmaxf(sT[2][2], sT[2][3]));
            float a3 = fmaxf(fmaxf(sT[3][0], sT[3][1]), fmaxf(sT[3][2], sT[3][3]));
            pm = fmaxf(fmaxf(a0, a1), fmaxf(a2, a3));
        }
        bool need = (pm > m_ + 30.f);
        if (__any((int)need)) {
            // full row max across the 4 q-lanes of row r
            float full = fmaxf(pm, __shfl_xor(pm, 16));
            full = fmaxf(full, __shfl_xor(full, 32));
            float nm = fmaxf(m_, full);
            float alpha = exp2f(m_ - nm);
            m_ = nm;
            // redistribute alpha to oacc/lacc rows (row q*4+reg lives at
            // lane with r' = q*4+reg; pick source lane q*16 + q*4 + reg)
            #pragma unroll
            for (int reg = 0; reg < 4; ++reg) {
                float areg = __shfl(alpha, q * 20 + reg);
                lacc[reg] *= areg;
                #pragma unroll
                for (int tt = 0; tt < 4; ++tt) oacc[tt][reg] *= areg;
            }
        }
        #pragma unroll
        for (int i = 0; i < 4; ++i)
            #pragma unroll
            for (int reg = 0; reg < 4; ++reg)
                sT[i][reg] = exp2f(sT[i][reg] - m_);

        // ---- PV: zero-shuffle.  pf chunk c = sT[c] packed: lane(q,r) holds
        //      P[row=r][key=c*16+q*4+j] = exactly the 16x16x16 A-frag. ----
        #pragma unroll
        for (int c = 0; c < 4; ++c) {
            union { uint2 u; short4v s; } pk;
            pk.u.x = packbf2(sT[c][0], sT[c][1]);
            pk.u.y = packbf2(sT[c][2], sT[c][3]);
            short4v pf = pk.s;
            lacc = mfma16(pf, bones4, lacc);
            #pragma unroll
            for (int tt = 0; tt < 4; ++tt) {
                short4v vfr = *(const short4v*)
                    &Vf[cur][vbase + (tt * 2 + (c >> 1)) * 512 + (c & 1) * 256];
                oacc[tt] = mfma16(pf, vfr, oacc[tt]);
            }
        }
    }

    // hazard guard for the inline-asm MFMA fallback (MFMA write -> VALU read)
    asm volatile("s_nop 7\n\ts_nop 7" :::);

    // ---- epilogue: O frag-order bf16 store (D layout unchanged) ----
    #pragma unroll
    for (int reg = 0; reg < 4; ++reg) {
        float inv = 1.f / lacc[reg];
        #pragma unroll
        for (int tt = 0; tt < 4; ++tt) {
            int ct = h * 2 + (tt >> 1);
            int lanep = ((tt & 1) * 2 + (r >> 3)) * 16 + q * 4 + reg;
            ob[((((size_t)b * 64 + nt) * 16 + ct) * 64 + lanep) * 8 + (r & 7)] =
                bf16rn(oacc[tt][reg] * inv);
        }
    }
}

// ---------------------------------------------------------------------------
// out_gemm: plain bf16 MFMA, double-buffered staging (unchanged).
// ---------------------------------------------------------------------------
__global__ __launch_bounds__(256) void out_gemm(const short* __restrict__ wof,
                                                const short* __restrict__ obf,
                                                float* __restrict__ out) {
    __shared__ short Ah[2][4096];
    __shared__ short Bh[2][4096];
    const int b = blockIdx.z, bd = blockIdx.y, bn = blockIdx.x;
    const int tid = threadIdx.x, w = tid >> 6, lane = tid & 63;
    const int q = lane >> 4, r = lane & 15;
    f32x4 acc[4];
    #pragma unroll
    for (int j = 0; j < 4; ++j) acc[j] = (f32x4){0.f, 0.f, 0.f, 0.f};

    for (int u = w; u < 8; u += 4) {
        size_t ga = ((size_t)((bd * 4 + (u >> 1)) * 16 + (u & 1))) * 512 + lane * 8;
        dma16(wof + ga, &Ah[0][u * 512]);
        size_t gb = ((size_t)((b * 64 + bn * 4 + (u >> 1)) * 16 + (u & 1))) * 512 + lane * 8;
        dma16(obf + gb, &Bh[0][u * 512]);
    }

    for (int it = 0; it < 8; ++it) {
        const int cur = it & 1;
        __syncthreads();
        if (it < 7) {
            for (int u = w; u < 8; u += 4) {
                size_t ga = ((size_t)((bd * 4 + (u >> 1)) * 16 + (it + 1) * 2 + (u & 1))) * 512 + lane * 8;
                dma16(wof + ga, &Ah[cur ^ 1][u * 512]);
                size_t gb = ((size_t)((b * 64 + bn * 4 + (u >> 1)) * 16 + (it + 1) * 2 + (u & 1))) * 512 + lane * 8;
                dma16(obf + gb, &Bh[cur ^ 1][u * 512]);
            }
        }
        #pragma unroll
        for (int kc = 0; kc < 2; ++kc) {
            short8 a = *(short8*)&Ah[cur][(w * 2 + kc) * 512 + lane * 8];
            #pragma unroll
            for (int tt = 0; tt < 4; ++tt) {
                short8 bb = *(short8*)&Bh[cur][(tt * 2 + kc) * 512 + lane * 8];
                acc[tt] = __builtin_amdgcn_mfma_f32_16x16x32_bf16(a, bb, acc[tt], 0, 0, 0);
            }
        }
    }
    const int d_base = bd * 64 + w * 16;
    #pragma unroll
    for (int reg = 0; reg < 4; ++reg)
        #pragma unroll
        for (int tt = 0; tt < 4; ++tt)
            out[((size_t)b * DOUT + d_base + q * 4 + reg) * NTOK
                + bn * 64 + tt * 16 + r] = acc[tt][reg];
}

// ---------------------------------------------------------------------------
extern "C" void kernel_launch(void* const* d_in, const int* in_sizes, int n_in,
                              void* d_out, int out_size, void* d_ws, size_t ws_size,
                              hipStream_t stream) {
    const float* x  = (const float*)d_in[0];
    const float* qp = (const float*)d_in[1];
    const float* kp = (const float*)d_in[2];
    const float* vp = (const float*)d_in[3];
    const float* op = (const float*)d_in[4];
    float* out = (float*)d_out;

    // workspace: 38.5 MB (proven R12/R13)
    short* Whi = (short*)d_ws;                 // 327,680
    short* Wlo = Whi + 327680;                 // 327,680
    short* Xhi = Wlo + 327680;                 // 4,194,304
    short* Xlo = Xhi + 4194304;                // 4,194,304
    short* Qhi = Xlo + 4194304;                // 4,194,304
    short* Qlo = Qhi + 4194304;                // 4,194,304
    short* Khi = Qlo + 4194304;                // 524,288
    short* Klo = Khi + 524288;                 // 524,288
    short* Vf  = Klo + 524288;                 // 524,288
    short* Wof = Vf  + 524288;                 // 262,144
    short* Ob  = Xhi;                          // alias: X dead after qkv_gemm

    prepack_all <<<1312, 256, 0, stream>>>(x, qp, kp, vp, op,
                                           Whi, Wlo, Xhi, Xlo, Wof);
    qkv_gemm    <<<640, 256, 0, stream>>>(Xhi, Xlo, Whi, Wlo,
                                          Khi, Klo, Vf, Qhi, Qlo);
    attn_mfma   <<<512, 512, 0, stream>>>(Qhi, Qlo, Khi, Klo, Vf, Ob);
    out_gemm    <<<dim3(16, 8, BATCH), 256, 0, stream>>>(Wof, Ob, out);
}